// Round 11
// baseline (8184.882 us; speedup 1.0000x reference)
//
#include <hip/hip_runtime.h>
#include <math.h>

#define B_    32
#define T_    128
#define IN_   256
#define H_    512
#define N_    128
#define R_    4
#define W_    64
#define RW_   256
#define FOUT_ 256
#define IF_   471
#define EPSF  1e-6f
#define KPAD  260
#define NBLK  176   // 0..127 gates (4 j each), 128..143 out (16 rows each), 144..175 mem (1 batch each)

typedef float v4f __attribute__((ext_vector_type(4)));

// ---------- workspace layout (float offsets) ----------
#define OFF_H0    0                      // h parity0: [32][512] batch-major
#define OFF_H1    16384
#define OFF_LR    32768                  // lr: [32][256] batch-major
#define OFF_FLAGA 40960                  // 144 slots * 32 uints
#define OFF_FLAGC (OFF_FLAGA + 144*32)   // 32 slots * 32 uints
#define WS_TOTAL  (OFF_FLAGC + 32*32)

__device__ __forceinline__ float sig_(float x)   { return 1.0f / (1.0f + expf(-x)); }
__device__ __forceinline__ float splus_(float x) { return fmaxf(x, 0.0f) + log1pf(expf(-fabsf(x))); }

// ---------- busy-burn: keep the CU's VALU busy while polling (DVFS: hold max DPM) ----------
__device__ __forceinline__ void burn() {
    float a = 1.0f;
    #pragma unroll
    for (int i = 0; i < 64; ++i) a = fmaf(a, 1.000001f, 1e-7f);
    asm volatile("" :: "v"(a));   // sink: keep the chain live
}

// ---------- coherent accessors (sc0 sc1: bypass L1/L2, IC-coherent) ----------
__device__ __forceinline__ float cload(const float* p) {
    return __hip_atomic_load(p, __ATOMIC_RELAXED, __HIP_MEMORY_SCOPE_AGENT);
}
__device__ __forceinline__ void cstore(float* p, float v) {
    __hip_atomic_store(p, v, __ATOMIC_RELAXED, __HIP_MEMORY_SCOPE_AGENT);
}
__device__ __forceinline__ unsigned uload(const unsigned* p) {
    return __hip_atomic_load(p, __ATOMIC_RELAXED, __HIP_MEMORY_SCOPE_AGENT);
}
__device__ __forceinline__ void ustore(unsigned* p, unsigned v) {
    __hip_atomic_store(p, v, __ATOMIC_RELAXED, __HIP_MEMORY_SCOPE_AGENT);
}

// batched coherent vec4 loads: 4 dwordx4 in flight, one waitcnt (inside same asm)
__device__ __forceinline__ void cload4x4(const float* p0, const float* p1,
                                         const float* p2, const float* p3,
                                         v4f& a, v4f& b, v4f& c, v4f& d) {
    asm volatile(
        "global_load_dwordx4 %0, %4, off sc0 sc1\n\t"
        "global_load_dwordx4 %1, %5, off sc0 sc1\n\t"
        "global_load_dwordx4 %2, %6, off sc0 sc1\n\t"
        "global_load_dwordx4 %3, %7, off sc0 sc1\n\t"
        "s_waitcnt vmcnt(0)"
        : "=&v"(a), "=&v"(b), "=&v"(c), "=&v"(d)
        : "v"(p0), "v"(p1), "v"(p2), "v"(p3)
        : "memory");
}
__device__ __forceinline__ v4f cload4(const float* p) {
    v4f v;
    asm volatile("global_load_dwordx4 %0, %1, off sc0 sc1\n\ts_waitcnt vmcnt(0)"
                 : "=&v"(v) : "v"(p) : "memory");
    return v;
}
__device__ __forceinline__ void cstore4(float* p, v4f v) {
    asm volatile("global_store_dwordx4 %0, %1, off sc0 sc1" :: "v"(p), "v"(v) : "memory");
}

__device__ __forceinline__ unsigned long long shflx64(unsigned long long v, int m) {
    unsigned int lo = (unsigned int)v, hi = (unsigned int)(v >> 32);
    lo = (unsigned int)__shfl_xor((int)lo, m);
    hi = (unsigned int)__shfl_xor((int)hi, m);
    return ((unsigned long long)hi << 32) | lo;
}

__global__ void k_init(float* p, int n) {
    for (int i = blockIdx.x * blockDim.x + threadIdx.x; i < n; i += gridDim.x * blockDim.x)
        p[i] = 0.0f;
}

// post: drain this block's sc1 stores, then one relaxed flag store
__device__ __forceinline__ void post_flag(unsigned* slot, unsigned val) {
    asm volatile("s_waitcnt vmcnt(0)" ::: "memory");
    __syncthreads();
    if (threadIdx.x == 0) ustore(slot, val);
}
// wait: thread i polls flag i (relaxed, busy-burn between polls); block barrier after
__device__ __forceinline__ void wait_flags(const unsigned* flags, int nf, unsigned val) {
    if ((int)threadIdx.x < nf) {
        while (uload(&flags[threadIdx.x * 32]) < val) burn();
    }
    __syncthreads();
}

// ---------- shared memory overlays ----------
struct SA {                       // gates / out blocks (~36.5 KB)
    float act[32 * KPAD];
    float sg[4][4][32];
    float cc[4][32];              // LSTM c state, LDS-resident (gates only)
    float hst[4][32];             // h staging for vectorized store
};
struct SM {                       // mem blocks, persistent across T (~115.7 KB)
    float link[N_][N_ + 1];
    float mem[N_ * (W_ + 1)];
    float hb[H_];
    float rw[R_*N_], fwd[R_*N_], bwd[R_*N_], cr[R_*N_];
    float cw[N_], usage[N_], alloc[N_], wwv[N_], prc[N_], minv[N_];
    float rkeys[R_*W_], wkey[W_], ev[W_], wv[W_];
    float rstr[R_], fg[R_], kinv[R_], m1[R_], modes[R_*3], sc[8];
    unsigned long long key[N_];
};

// ---- stage a [32][256] batch-major tile into lds[b][k] ----
__device__ __forceinline__ void stage_x(const float* __restrict__ x, int t, float* lds, int tid) {
    #pragma unroll
    for (int i = 0; i < 8; ++i) {
        int f = i * 256 + tid;
        int b = f >> 6, k4 = (f & 63) << 2;
        v4f v = *reinterpret_cast<const v4f*>(x + ((size_t)b * T_ + t) * IN_ + k4);
        *reinterpret_cast<v4f*>(&lds[b * KPAD + k4]) = v;
    }
}
__device__ __forceinline__ void stage_coh(const float* __restrict__ src, int rowstride,
                                          int colofs, float* lds, int tid) {
    int f0 = 0*256 + tid, f1 = 1*256 + tid, f2 = 2*256 + tid, f3 = 3*256 + tid;
    int f4 = 4*256 + tid, f5 = 5*256 + tid, f6 = 6*256 + tid, f7 = 7*256 + tid;
    const float* p0 = src + (size_t)(f0 >> 6) * rowstride + colofs + ((f0 & 63) << 2);
    const float* p1 = src + (size_t)(f1 >> 6) * rowstride + colofs + ((f1 & 63) << 2);
    const float* p2 = src + (size_t)(f2 >> 6) * rowstride + colofs + ((f2 & 63) << 2);
    const float* p3 = src + (size_t)(f3 >> 6) * rowstride + colofs + ((f3 & 63) << 2);
    const float* p4 = src + (size_t)(f4 >> 6) * rowstride + colofs + ((f4 & 63) << 2);
    const float* p5 = src + (size_t)(f5 >> 6) * rowstride + colofs + ((f5 & 63) << 2);
    const float* p6 = src + (size_t)(f6 >> 6) * rowstride + colofs + ((f6 & 63) << 2);
    const float* p7 = src + (size_t)(f7 >> 6) * rowstride + colofs + ((f7 & 63) << 2);
    v4f r0, r1, r2, r3, r4, r5, r6, r7;
    cload4x4(p0, p1, p2, p3, r0, r1, r2, r3);
    cload4x4(p4, p5, p6, p7, r4, r5, r6, r7);
    *reinterpret_cast<v4f*>(&lds[(f0 >> 6) * KPAD + ((f0 & 63) << 2)]) = r0;
    *reinterpret_cast<v4f*>(&lds[(f1 >> 6) * KPAD + ((f1 & 63) << 2)]) = r1;
    *reinterpret_cast<v4f*>(&lds[(f2 >> 6) * KPAD + ((f2 & 63) << 2)]) = r2;
    *reinterpret_cast<v4f*>(&lds[(f3 >> 6) * KPAD + ((f3 & 63) << 2)]) = r3;
    *reinterpret_cast<v4f*>(&lds[(f4 >> 6) * KPAD + ((f4 & 63) << 2)]) = r4;
    *reinterpret_cast<v4f*>(&lds[(f5 >> 6) * KPAD + ((f5 & 63) << 2)]) = r5;
    *reinterpret_cast<v4f*>(&lds[(f6 >> 6) * KPAD + ((f6 & 63) << 2)]) = r6;
    *reinterpret_cast<v4f*>(&lds[(f7 >> 6) * KPAD + ((f7 & 63) << 2)]) = r7;
}

__device__ __forceinline__ void tile_mac4(const float* lds,
        const float* __restrict__ w0p, const float* __restrict__ w1p,
        const float* __restrict__ w2p, const float* __restrict__ w3p,
        int lane, float* v)
{
    v4f w0 = *reinterpret_cast<const v4f*>(w0p + lane * 4);
    v4f w1 = *reinterpret_cast<const v4f*>(w1p + lane * 4);
    v4f w2 = *reinterpret_cast<const v4f*>(w2p + lane * 4);
    v4f w3 = *reinterpret_cast<const v4f*>(w3p + lane * 4);
    #pragma unroll
    for (int b = 0; b < 32; ++b) {
        v4f a = *reinterpret_cast<const v4f*>(lds + b * KPAD + lane * 4);
        v[0*32+b] = fmaf(w0.w, a.w, fmaf(w0.z, a.z, fmaf(w0.y, a.y, fmaf(w0.x, a.x, v[0*32+b]))));
        v[1*32+b] = fmaf(w1.w, a.w, fmaf(w1.z, a.z, fmaf(w1.y, a.y, fmaf(w1.x, a.x, v[1*32+b]))));
        v[2*32+b] = fmaf(w2.w, a.w, fmaf(w2.z, a.z, fmaf(w2.y, a.y, fmaf(w2.x, a.x, v[2*32+b]))));
        v[3*32+b] = fmaf(w3.w, a.w, fmaf(w3.z, a.z, fmaf(w3.y, a.y, fmaf(w3.x, a.x, v[3*32+b]))));
    }
}

__device__ __forceinline__ void fold128(float* v, int lane) {
    #define FOLD_STAGE(D, HALF) { _Pragma("unroll") \
        for (int i = 0; i < HALF; ++i) { \
            float a_ = v[i], c_ = v[i + HALF]; \
            float t_ = (lane & D) ? a_ : c_; \
            t_ = __shfl_xor(t_, D); \
            v[i] = (lane & D) ? (c_ + t_) : (a_ + t_); } }
    FOLD_STAGE(32, 64) FOLD_STAGE(16, 32) FOLD_STAGE(8, 16)
    FOLD_STAGE(4, 8)   FOLD_STAGE(2, 4)   FOLD_STAGE(1, 2)
    #undef FOLD_STAGE
}

// ---------- memory machine (batch b), state fully LDS-resident ----------
__device__ void mem_body(SM& sm, int b, int tid,
        const float* __restrict__ Wif, const float* __restrict__ bif,
        const float* __restrict__ gh, float* __restrict__ glr)
{
    const int lane = tid & 63, wid = tid >> 6;

    // 0. stage h(t) row b (vectorized coherent: 128 dwordx4)
    if (tid < 128) {
        v4f v4 = cload4(&gh[(size_t)b * H_ + tid * 4]);
        *reinterpret_cast<v4f*>(&sm.hb[tid * 4]) = v4;
    }
    __syncthreads();

    // 1. xi GEMV (Wif stream from L2) + parse
    #pragma unroll
    for (int s = 0; s < 2; ++s) {
        int i = tid + s * 256;
        if (i < IF_) {
            const v4f* wr = reinterpret_cast<const v4f*>(Wif + (size_t)i * H_);
            float a0 = 0.f, a1 = 0.f, a2 = 0.f, a3 = 0.f;
            #pragma unroll 8
            for (int q = 0; q < H_/4; ++q) {
                v4f w4 = wr[q];
                a0 = fmaf(w4.x, sm.hb[q*4+0], a0);
                a1 = fmaf(w4.y, sm.hb[q*4+1], a1);
                a2 = fmaf(w4.z, sm.hb[q*4+2], a2);
                a3 = fmaf(w4.w, sm.hb[q*4+3], a3);
            }
            float vv = (a0 + a1) + (a2 + a3) + bif[i];
            if      (i < 256) sm.rkeys[i]     = tanhf(vv);
            else if (i < 260) sm.rstr[i-256]  = splus_(vv);
            else if (i < 324) sm.wkey[i-260]  = tanhf(vv);
            else if (i < 325) sm.sc[0]        = splus_(vv);
            else if (i < 389) sm.ev[i-325]    = sig_(vv);
            else if (i < 453) sm.wv[i-389]    = tanhf(vv);
            else if (i < 457) sm.fg[i-453]    = sig_(vv);
            else if (i < 458) sm.sc[1]        = sig_(vv);
            else if (i < 459) sm.sc[2]        = sig_(vv);
            else              sm.modes[i-459] = vv;
        }
    }
    __syncthreads();

    // 2. usage update, sort key, pre-update norms, head norms, modes softmax
    unsigned long long key = ~0ull;
    if (tid < N_) {
        float p = 1.0f;
        #pragma unroll
        for (int r = 0; r < R_; ++r) p *= 1.0f - sm.fg[r] * sm.rw[r*N_ + tid];
        float uo = sm.usage[tid], w0 = sm.wwv[tid];
        float u = (uo + w0 - uo*w0) * p;
        sm.usage[tid] = u;
        unsigned int fb = __float_as_uint(u);
        fb = (fb & 0x80000000u) ? ~fb : (fb | 0x80000000u);
        key = ((unsigned long long)fb << 32) | (unsigned int)tid;
        float s = 0.0f;
        for (int w = 0; w < W_; ++w) { float m = sm.mem[tid*(W_+1)+w]; s += m*m; }
        sm.minv[tid] = 1.0f / (sqrtf(s) + EPSF);
    }
    if (tid >= 128 && tid < 128 + R_) {
        int r = tid - 128;
        float s = 0.0f;
        for (int w = 0; w < W_; ++w) { float kv = sm.rkeys[r*W_+w]; s += kv*kv; }
        sm.kinv[r] = 1.0f / (sqrtf(s) + EPSF);
    }
    if (tid == 132) {
        float s = 0.0f;
        for (int w = 0; w < W_; ++w) s += sm.wkey[w]*sm.wkey[w];
        sm.sc[5] = 1.0f / (sqrtf(s) + EPSF);
    }
    if (tid >= 136 && tid < 136 + R_) {
        int r = tid - 136;
        float m0 = sm.modes[r*3], m1 = sm.modes[r*3+1], m2 = sm.modes[r*3+2];
        float mx = fmaxf(m0, fmaxf(m1, m2));
        float e0 = expf(m0-mx), e1 = expf(m1-mx), e2 = expf(m2-mx);
        float inv = 1.0f / (e0 + e1 + e2);
        sm.modes[r*3] = e0*inv; sm.modes[r*3+1] = e1*inv; sm.modes[r*3+2] = e2*inv;
    }
    __syncthreads();

    // 3. write-content dot + register bitonic sort
    if (tid < N_) {
        float d = 0.0f;
        for (int w = 0; w < W_; ++w) d += sm.wkey[w] * sm.mem[tid*(W_+1)+w];
        sm.cw[tid] = d * sm.minv[tid] * sm.sc[5] * sm.sc[0];
    }
    for (int k = 2; k <= N_; k <<= 1) {
        for (int j = k >> 1; j > 0; j >>= 1) {
            unsigned long long pk;
            if (j == 64) {
                if (tid < N_) sm.key[tid] = key;
                __syncthreads();
                pk = (tid < N_) ? sm.key[tid ^ 64] : key;
                __syncthreads();
            } else {
                pk = shflx64(key, j);
            }
            bool lower = (tid & j) == 0;
            bool asc   = (tid & k) == 0;
            if ((key > pk) == (lower == asc)) key = pk;
        }
    }

    // 4. allocation via shfl product-scan; wave2 does write softmax
    float su = 0.0f, ex = 1.0f; int sidx = 0;
    if (tid < N_) {
        sidx = (int)(key & 0xffffffffu);
        su = sm.usage[sidx];
        float p = su;
        #pragma unroll
        for (int off = 1; off < 64; off <<= 1) {
            float pv = __shfl_up(p, off);
            if (lane >= off) p *= pv;
        }
        if (tid == 63) sm.sc[7] = p;
        float e = __shfl_up(p, 1);
        ex = (lane == 0) ? 1.0f : e;
    }
    __syncthreads();
    if (tid < N_) {
        if (tid >= 64) ex *= sm.sc[7];
        sm.alloc[sidx] = (1.0f - su) * ex;
    }
    if (wid == 2) {
        float v0 = sm.cw[lane], v1 = sm.cw[lane+64];
        float m = fmaxf(v0, v1);
        #pragma unroll
        for (int o = 32; o >= 1; o >>= 1) m = fmaxf(m, __shfl_xor(m, o));
        float e0 = expf(v0 - m), e1 = expf(v1 - m);
        float s = e0 + e1;
        #pragma unroll
        for (int o = 32; o >= 1; o >>= 1) s += __shfl_xor(s, o);
        sm.cw[lane] = e0; sm.cw[lane+64] = e1;
        if (lane == 0) sm.sc[4] = 1.0f / s;
    }
    __syncthreads();

    // 5. write weighting
    if (tid < N_) {
        float cwn = sm.cw[tid] * sm.sc[4];
        sm.wwv[tid] = sm.sc[2] * (sm.sc[1] * sm.alloc[tid] + (1.0f - sm.sc[1]) * cwn);
    }
    __syncthreads();

    // 6. memory update (in place) + sum_ww (wave3)
    for (int i = tid; i < N_*W_; i += 256) {
        int n = i >> 6, w = i & 63;
        float m = sm.mem[n*(W_+1)+w];
        sm.mem[n*(W_+1)+w] = m * (1.0f - sm.wwv[n]*sm.ev[w]) + sm.wwv[n]*sm.wv[w];
    }
    if (wid == 3) {
        float s = sm.wwv[lane] + sm.wwv[lane+64];
        #pragma unroll
        for (int o = 32; o >= 1; o >>= 1) s += __shfl_xor(s, o);
        if (lane == 0) sm.sc[6] = s;
    }
    __syncthreads();

    // 7. link update (LDS, in place)
    for (int i = tid; i < N_*N_; i += 256) {
        int row = i >> 7, col = i & 127;
        float wwr = sm.wwv[row];
        float nv = (1.0f - wwr - sm.wwv[col]) * sm.link[row][col] + wwr * sm.prc[col];
        if (row == col) nv = 0.0f;
        sm.link[row][col] = nv;
    }
    __syncthreads();

    // 7b. fwd/bwd dot passes
    for (int i = tid; i < R_*N_; i += 256) {
        int r = i >> 7, q = i & 127;
        float accf = 0.0f, accb = 0.0f;
        #pragma unroll 4
        for (int m2 = 0; m2 < 128; ++m2) {
            float rv = sm.rw[r*N_ + m2];
            accf = fmaf(sm.link[q][m2], rv, accf);
            accb = fmaf(sm.link[m2][q], rv, accb);
        }
        sm.fwd[i] = accf;
        sm.bwd[i] = accb;
    }
    __syncthreads();

    // 8. precedence + post-update norms
    if (tid < N_) {
        sm.prc[tid] = (1.0f - sm.sc[6]) * sm.prc[tid] + sm.wwv[tid];
        float s = 0.0f;
        for (int w = 0; w < W_; ++w) { float m = sm.mem[tid*(W_+1)+w]; s += m*m; }
        sm.minv[tid] = 1.0f / (sqrtf(s) + EPSF);
    }
    __syncthreads();

    // 9. read-content dots
    for (int i = tid; i < R_*N_; i += 256) {
        int r = i >> 7, n = i & 127;
        float d = 0.0f;
        for (int w = 0; w < W_; ++w) d += sm.rkeys[r*W_+w] * sm.mem[n*(W_+1)+w];
        sm.cr[i] = d * sm.minv[n] * sm.kinv[r] * sm.rstr[r];
    }
    __syncthreads();

    // 10. per-head softmax (wave = head)
    {
        int r = wid;
        float v0 = sm.cr[r*N_ + lane], v1 = sm.cr[r*N_ + lane + 64];
        float m = fmaxf(v0, v1);
        #pragma unroll
        for (int o = 32; o >= 1; o >>= 1) m = fmaxf(m, __shfl_xor(m, o));
        float e0 = expf(v0 - m), e1 = expf(v1 - m);
        float s = e0 + e1;
        #pragma unroll
        for (int o = 32; o >= 1; o >>= 1) s += __shfl_xor(s, o);
        sm.cr[r*N_ + lane] = e0; sm.cr[r*N_ + lane + 64] = e1;
        if (lane == 0) sm.m1[r] = sm.modes[r*3+1] / s;
    }
    __syncthreads();

    // 11. new read weights (persist)
    for (int i = tid; i < R_*N_; i += 256) {
        int r = i >> 7;
        sm.rw[i] = sm.modes[r*3] * sm.bwd[i] + sm.m1[r] * sm.cr[i] + sm.modes[r*3+2] * sm.fwd[i];
    }
    __syncthreads();

    // 12. read vectors -> lr[b][i] (coherent)
    for (int i = tid; i < R_*W_; i += 256) {
        int r = i >> 6, w = i & 63;
        float d = 0.0f;
        for (int n = 0; n < N_; ++n) d += sm.rw[r*N_ + n] * sm.mem[n*(W_+1)+w];
        cstore(&glr[(size_t)b * RW_ + i], d);
    }
}

// ---------- persistent kernel ----------
__global__ __launch_bounds__(256, 1) void k_fused(
        const float* __restrict__ x, const float* __restrict__ Wih,
        const float* __restrict__ Whh, const float* __restrict__ bih,
        const float* __restrict__ bhh, const float* __restrict__ Wif,
        const float* __restrict__ bif, const float* __restrict__ Wemb,
        const float* __restrict__ bemb, float* __restrict__ out,
        float* __restrict__ ws)
{
    __shared__ __align__(16) char smem_raw[(sizeof(SM) > sizeof(SA)) ? sizeof(SM) : sizeof(SA)];
    SA& sa = *reinterpret_cast<SA*>(smem_raw);
    SM& sm = *reinterpret_cast<SM*>(smem_raw);

    const int bid = blockIdx.x, tid = threadIdx.x;
    const int lane = tid & 63, wid = tid >> 6;

    float* h0 = ws + OFF_H0;
    float* h1 = ws + OFF_H1;
    float* lr = ws + OFF_LR;
    unsigned* flagA = (unsigned*)(ws + OFF_FLAGA);
    unsigned* flagC = (unsigned*)(ws + OFF_FLAGC);

    if (bid < 128) {
        // ======================= GATES block: j = bid*4 + wid =======================
        const int j = bid * 4 + wid;
        if (tid < 128) sa.cc[tid >> 5][tid & 31] = 0.0f;
        float b0 = bih[j]        + bhh[j];
        float b1 = bih[H_ + j]   + bhh[H_ + j];
        float b2 = bih[2*H_ + j] + bhh[2*H_ + j];
        float b3 = bih[3*H_ + j] + bhh[3*H_ + j];
        __syncthreads();

        for (int t = 0; t < T_; ++t) {
            const float* hprev = (t & 1) ? h1 : h0;
            float*       hnew  = (t & 1) ? h0 : h1;
            float v[128];
            #pragma unroll
            for (int i = 0; i < 128; ++i) v[i] = 0.0f;

            // x tile (no dependency)
            stage_x(x, t, sa.act, tid);
            __syncthreads();
            tile_mac4(sa.act, Wih + (size_t)(0*H_+j)*512, Wih + (size_t)(1*H_+j)*512,
                              Wih + (size_t)(2*H_+j)*512, Wih + (size_t)(3*H_+j)*512, lane, v);
            // h(t-1) tiles — only need all GATES flags >= t (overlaps with mem(t-1)!)
            if (tid < 128) { while (uload(&flagA[tid*32]) < (unsigned)t) burn(); }
            __syncthreads();
            stage_coh(hprev, H_, 0, sa.act, tid);
            __syncthreads();
            tile_mac4(sa.act, Whh + (size_t)(0*H_+j)*512, Whh + (size_t)(1*H_+j)*512,
                              Whh + (size_t)(2*H_+j)*512, Whh + (size_t)(3*H_+j)*512, lane, v);
            __syncthreads();
            stage_coh(hprev, H_, 256, sa.act, tid);
            __syncthreads();
            tile_mac4(sa.act, Whh + (size_t)(0*H_+j)*512 + 256, Whh + (size_t)(1*H_+j)*512 + 256,
                              Whh + (size_t)(2*H_+j)*512 + 256, Whh + (size_t)(3*H_+j)*512 + 256, lane, v);
            // lr(t-1) tile — needs mem(t-1) done
            if (tid < 32) { while (uload(&flagC[tid*32]) < (unsigned)t) burn(); }
            __syncthreads();
            stage_coh(lr, RW_, 0, sa.act, tid);
            __syncthreads();
            tile_mac4(sa.act, Wih + (size_t)(0*H_+j)*512 + 256, Wih + (size_t)(1*H_+j)*512 + 256,
                              Wih + (size_t)(2*H_+j)*512 + 256, Wih + (size_t)(3*H_+j)*512 + 256, lane, v);
            fold128(v, lane);
            int r = (lane >> 4) & 3, bb0 = (lane & 15) * 2;
            sa.sg[wid][r][bb0]     = v[0];
            sa.sg[wid][r][bb0 + 1] = v[1];
            __syncthreads();
            if (lane < 32) {
                int b = lane;
                float ai = sa.sg[wid][0][b] + b0;
                float af = sa.sg[wid][1][b] + b1;
                float ag = sa.sg[wid][2][b] + b2;
                float ao = sa.sg[wid][3][b] + b3;
                float ig = sig_(ai), fg = sig_(af), gg = tanhf(ag), og = sig_(ao);
                float cn = fg * sa.cc[wid][b] + ig * gg;
                sa.cc[wid][b] = cn;
                sa.hst[wid][b] = og * tanhf(cn);
            }
            __syncthreads();
            if (tid < 32) {
                int b = tid;
                v4f hv;
                hv.x = sa.hst[0][b]; hv.y = sa.hst[1][b];
                hv.z = sa.hst[2][b]; hv.w = sa.hst[3][b];
                cstore4(&hnew[(size_t)b * H_ + bid * 4], hv);
            }
            post_flag(&flagA[bid * 32], (unsigned)(t + 1));
        }
    } else if (bid < 144) {
        // ======================= OUT block: rows (bid-128)*16 + wid*4 ===============
        const int rb = (bid - 128) * 16 + wid * 4;
        const float* w0 = Wemb + (size_t)(rb + 0) * 768;
        const float* w1 = Wemb + (size_t)(rb + 1) * 768;
        const float* w2 = Wemb + (size_t)(rb + 2) * 768;
        const float* w3 = Wemb + (size_t)(rb + 3) * 768;

        for (int t = 0; t < T_; ++t) {
            const float* hprev = (t & 1) ? h1 : h0;
            if (t > 0) {
                float v[128];
                #pragma unroll
                for (int i = 0; i < 128; ++i) v[i] = 0.0f;
                if (tid < 128) { while (uload(&flagA[tid*32]) < (unsigned)t) burn(); }
                __syncthreads();
                stage_coh(hprev, H_, 0, sa.act, tid);
                __syncthreads();
                tile_mac4(sa.act, w0, w1, w2, w3, lane, v);
                __syncthreads();
                stage_coh(hprev, H_, 256, sa.act, tid);
                __syncthreads();
                tile_mac4(sa.act, w0 + 256, w1 + 256, w2 + 256, w3 + 256, lane, v);
                if (tid < 32) { while (uload(&flagC[tid*32]) < (unsigned)t) burn(); }
                __syncthreads();
                stage_coh(lr, RW_, 0, sa.act, tid);
                __syncthreads();
                tile_mac4(sa.act, w0 + 512, w1 + 512, w2 + 512, w3 + 512, lane, v);
                fold128(v, lane);
                int rloc = (lane >> 4) & 3, bb0 = (lane & 15) * 2;
                int row = rb + rloc;
                float bb = bemb[row];
                out[((size_t)bb0       * T_ + (t-1)) * FOUT_ + row] = v[0] + bb;
                out[((size_t)(bb0 + 1) * T_ + (t-1)) * FOUT_ + row] = v[1] + bb;
            }
            post_flag(&flagA[bid * 32], (unsigned)(t + 1));
        }
        // tail: out(T-1) from h(T-1)=h0, lr(T-1)
        {
            if (tid < 32) { while (uload(&flagC[tid*32]) < (unsigned)T_) burn(); }
            __syncthreads();
            float v[128];
            #pragma unroll
            for (int i = 0; i < 128; ++i) v[i] = 0.0f;
            stage_coh(h0, H_, 0, sa.act, tid);
            __syncthreads();
            tile_mac4(sa.act, w0, w1, w2, w3, lane, v);
            __syncthreads();
            stage_coh(h0, H_, 256, sa.act, tid);
            __syncthreads();
            tile_mac4(sa.act, w0 + 256, w1 + 256, w2 + 256, w3 + 256, lane, v);
            __syncthreads();
            stage_coh(lr, RW_, 0, sa.act, tid);
            __syncthreads();
            tile_mac4(sa.act, w0 + 512, w1 + 512, w2 + 512, w3 + 512, lane, v);
            fold128(v, lane);
            int rloc = (lane >> 4) & 3, bb0 = (lane & 15) * 2;
            int row = rb + rloc;
            float bb = bemb[row];
            out[((size_t)bb0       * T_ + (T_-1)) * FOUT_ + row] = v[0] + bb;
            out[((size_t)(bb0 + 1) * T_ + (T_-1)) * FOUT_ + row] = v[1] + bb;
        }
    } else {
        // ======================= MEM block: batch b = bid-144 =======================
        const int b = bid - 144;
        float* z = (float*)&sm;
        for (int i = tid; i < (int)(sizeof(SM)/4); i += 256) z[i] = 0.0f;
        __syncthreads();

        for (int t = 0; t < T_; ++t) {
            float* hnew = (t & 1) ? h0 : h1;
            wait_flags(flagA, 144, (unsigned)(t + 1));   // all h(t) stored + lr(t-1) consumed
            mem_body(sm, b, tid, Wif, bif, hnew, lr);
            post_flag(&flagC[b * 32], (unsigned)(t + 1));
        }
    }
}

extern "C" void kernel_launch(void* const* d_in, const int* in_sizes, int n_in,
                              void* d_out, int out_size, void* d_ws, size_t ws_size,
                              hipStream_t stream)
{
    const float* x    = (const float*)d_in[0];
    const float* Wih  = (const float*)d_in[1];
    const float* Whh  = (const float*)d_in[2];
    const float* bih  = (const float*)d_in[3];
    const float* bhh  = (const float*)d_in[4];
    const float* Wif  = (const float*)d_in[5];
    const float* bif  = (const float*)d_in[6];
    const float* Wemb = (const float*)d_in[7];
    const float* bemb = (const float*)d_in[8];
    float* out = (float*)d_out;
    float* ws  = (float*)d_ws;

    k_init<<<64, 256, 0, stream>>>(ws, WS_TOTAL);

    k_fused<<<dim3(NBLK), dim3(256), 0, stream>>>(x, Wih, Whh, bih, bhh,
                                                  Wif, bif, Wemb, bemb, out, ws);
}

// Round 13
// 5422.885 us; speedup vs baseline: 1.5093x; 1.5093x over previous
//
#include <hip/hip_runtime.h>
#include <math.h>

#define B_    32
#define T_    128
#define IN_   256
#define H_    512
#define N_    128
#define R_    4
#define W_    64
#define RW_   256
#define FOUT_ 256
#define IF_   471
#define XIP   480
#define EPSF  1e-6f
#define KPAD  260
#define NBLK  208   // 0..127 gates, 128..143 out, 144..175 xi, 176..207 mem

typedef float v4f __attribute__((ext_vector_type(4)));

// ---------- workspace layout (float offsets) ----------
#define OFF_H0    0                      // h parity0: [32][512] batch-major
#define OFF_H1    16384
#define OFF_LR    32768                  // lr: [32][256] batch-major
#define OFF_XI    40960                  // xi: [32][480] batch-major (pre-activation+bias)
#define OFF_FLAGA (OFF_XI + 32*XIP)      // 144 slots * 32 uints (gates 0..127, out 128..143)
#define OFF_FLAGX (OFF_FLAGA + 144*32)   // 32 slots * 32
#define OFF_FLAGC (OFF_FLAGX + 32*32)    // 32 slots * 32
#define WS_TOTAL  (OFF_FLAGC + 32*32)

__device__ __forceinline__ float sig_(float x)   { return 1.0f / (1.0f + expf(-x)); }
__device__ __forceinline__ float splus_(float x) { return fmaxf(x, 0.0f) + log1pf(expf(-fabsf(x))); }

// ---------- uncached (sc0 sc1, IC-coherent) accessors — ALL cross-block data ----------
__device__ __forceinline__ void cstore(float* p, float v) {
    __hip_atomic_store(p, v, __ATOMIC_RELAXED, __HIP_MEMORY_SCOPE_AGENT);
}
__device__ __forceinline__ unsigned uload(const unsigned* p) {
    return __hip_atomic_load(p, __ATOMIC_RELAXED, __HIP_MEMORY_SCOPE_AGENT);
}
__device__ __forceinline__ void ustore(unsigned* p, unsigned v) {
    __hip_atomic_store(p, v, __ATOMIC_RELAXED, __HIP_MEMORY_SCOPE_AGENT);
}
__device__ __forceinline__ void cload4x4(const float* p0, const float* p1,
                                         const float* p2, const float* p3,
                                         v4f& a, v4f& b, v4f& c, v4f& d) {
    asm volatile(
        "global_load_dwordx4 %0, %4, off sc0 sc1\n\t"
        "global_load_dwordx4 %1, %5, off sc0 sc1\n\t"
        "global_load_dwordx4 %2, %6, off sc0 sc1\n\t"
        "global_load_dwordx4 %3, %7, off sc0 sc1\n\t"
        "s_waitcnt vmcnt(0)"
        : "=&v"(a), "=&v"(b), "=&v"(c), "=&v"(d)
        : "v"(p0), "v"(p1), "v"(p2), "v"(p3)
        : "memory");
}
__device__ __forceinline__ v4f cload4(const float* p) {
    v4f v;
    asm volatile("global_load_dwordx4 %0, %1, off sc0 sc1\n\ts_waitcnt vmcnt(0)"
                 : "=&v"(v) : "v"(p) : "memory");
    return v;
}
__device__ __forceinline__ void cstore4(float* p, v4f v) {
    asm volatile("global_store_dwordx4 %0, %1, off sc0 sc1" :: "v"(p), "v"(v) : "memory");
}

__device__ __forceinline__ unsigned long long shflx64(unsigned long long v, int m) {
    unsigned int lo = (unsigned int)v, hi = (unsigned int)(v >> 32);
    lo = (unsigned int)__shfl_xor((int)lo, m);
    hi = (unsigned int)__shfl_xor((int)hi, m);
    return ((unsigned long long)hi << 32) | lo;
}

__global__ void k_init(float* p, int n) {
    for (int i = blockIdx.x * blockDim.x + threadIdx.x; i < n; i += gridDim.x * blockDim.x)
        p[i] = 0.0f;
}

__device__ __forceinline__ void post_flag(unsigned* slot, unsigned val) {
    asm volatile("s_waitcnt vmcnt(0)" ::: "memory");
    __syncthreads();
    if (threadIdx.x == 0) ustore(slot, val);
}

// ---------- shared memory overlays ----------
struct SA {                       // gates / out / xi blocks (~36.5 KB)
    float act[32 * KPAD];
    float sg[4][4][32];
    float cc[4][32];
    float hst[4][32];
};
struct SM {                       // mem blocks, persistent (~114 KB)
    float link[N_][N_ + 1];
    float mem[N_ * (W_ + 1)];
    float sxi[XIP];
    float rw[R_*N_], fwd[R_*N_], bwd[R_*N_], cr[R_*N_];
    float cw[N_], usage[N_], alloc[N_], wwv[N_], prc[N_], minv[N_];
    float rkeys[R_*W_], wkey[W_], ev[W_], wv[W_];
    float rstr[R_], fg[R_], kinv[R_], m1[R_], modes[R_*3], sc[8];
    unsigned long long key[N_];
};

// ---- stage a [32][256] col-slice of a batch-major matrix into lds[b][k] (uncached) ----
__device__ __forceinline__ void stage_coh(const float* __restrict__ src, int rowstride,
                                          int colofs, float* lds, int tid) {
    int f0 = 0*256 + tid, f1 = 1*256 + tid, f2 = 2*256 + tid, f3 = 3*256 + tid;
    int f4 = 4*256 + tid, f5 = 5*256 + tid, f6 = 6*256 + tid, f7 = 7*256 + tid;
    const float* p0 = src + (size_t)(f0 >> 6) * rowstride + colofs + ((f0 & 63) << 2);
    const float* p1 = src + (size_t)(f1 >> 6) * rowstride + colofs + ((f1 & 63) << 2);
    const float* p2 = src + (size_t)(f2 >> 6) * rowstride + colofs + ((f2 & 63) << 2);
    const float* p3 = src + (size_t)(f3 >> 6) * rowstride + colofs + ((f3 & 63) << 2);
    const float* p4 = src + (size_t)(f4 >> 6) * rowstride + colofs + ((f4 & 63) << 2);
    const float* p5 = src + (size_t)(f5 >> 6) * rowstride + colofs + ((f5 & 63) << 2);
    const float* p6 = src + (size_t)(f6 >> 6) * rowstride + colofs + ((f6 & 63) << 2);
    const float* p7 = src + (size_t)(f7 >> 6) * rowstride + colofs + ((f7 & 63) << 2);
    v4f r0, r1, r2, r3, r4, r5, r6, r7;
    cload4x4(p0, p1, p2, p3, r0, r1, r2, r3);
    cload4x4(p4, p5, p6, p7, r4, r5, r6, r7);
    *reinterpret_cast<v4f*>(&lds[(f0 >> 6) * KPAD + ((f0 & 63) << 2)]) = r0;
    *reinterpret_cast<v4f*>(&lds[(f1 >> 6) * KPAD + ((f1 & 63) << 2)]) = r1;
    *reinterpret_cast<v4f*>(&lds[(f2 >> 6) * KPAD + ((f2 & 63) << 2)]) = r2;
    *reinterpret_cast<v4f*>(&lds[(f3 >> 6) * KPAD + ((f3 & 63) << 2)]) = r3;
    *reinterpret_cast<v4f*>(&lds[(f4 >> 6) * KPAD + ((f4 & 63) << 2)]) = r4;
    *reinterpret_cast<v4f*>(&lds[(f5 >> 6) * KPAD + ((f5 & 63) << 2)]) = r5;
    *reinterpret_cast<v4f*>(&lds[(f6 >> 6) * KPAD + ((f6 & 63) << 2)]) = r6;
    *reinterpret_cast<v4f*>(&lds[(f7 >> 6) * KPAD + ((f7 & 63) << 2)]) = r7;
}
__device__ __forceinline__ void stage_x(const float* __restrict__ x, int t, float* lds, int tid) {
    #pragma unroll
    for (int i = 0; i < 8; ++i) {
        int f = i * 256 + tid;
        int b = f >> 6, k4 = (f & 63) << 2;
        v4f v = *reinterpret_cast<const v4f*>(x + ((size_t)b * T_ + t) * IN_ + k4);
        *reinterpret_cast<v4f*>(&lds[b * KPAD + k4]) = v;
    }
}

__device__ __forceinline__ void tile_mac4(const float* lds,
        const float* __restrict__ w0p, const float* __restrict__ w1p,
        const float* __restrict__ w2p, const float* __restrict__ w3p,
        int lane, float* v)
{
    v4f w0 = *reinterpret_cast<const v4f*>(w0p + lane * 4);
    v4f w1 = *reinterpret_cast<const v4f*>(w1p + lane * 4);
    v4f w2 = *reinterpret_cast<const v4f*>(w2p + lane * 4);
    v4f w3 = *reinterpret_cast<const v4f*>(w3p + lane * 4);
    #pragma unroll
    for (int b = 0; b < 32; ++b) {
        v4f a = *reinterpret_cast<const v4f*>(lds + b * KPAD + lane * 4);
        v[0*32+b] = fmaf(w0.w, a.w, fmaf(w0.z, a.z, fmaf(w0.y, a.y, fmaf(w0.x, a.x, v[0*32+b]))));
        v[1*32+b] = fmaf(w1.w, a.w, fmaf(w1.z, a.z, fmaf(w1.y, a.y, fmaf(w1.x, a.x, v[1*32+b]))));
        v[2*32+b] = fmaf(w2.w, a.w, fmaf(w2.z, a.z, fmaf(w2.y, a.y, fmaf(w2.x, a.x, v[2*32+b]))));
        v[3*32+b] = fmaf(w3.w, a.w, fmaf(w3.z, a.z, fmaf(w3.y, a.y, fmaf(w3.x, a.x, v[3*32+b]))));
    }
}

__device__ __forceinline__ void fold128(float* v, int lane) {
    #define FOLD_STAGE(D, HALF) { _Pragma("unroll") \
        for (int i = 0; i < HALF; ++i) { \
            float a_ = v[i], c_ = v[i + HALF]; \
            float t_ = (lane & D) ? a_ : c_; \
            t_ = __shfl_xor(t_, D); \
            v[i] = (lane & D) ? (c_ + t_) : (a_ + t_); } }
    FOLD_STAGE(32, 64) FOLD_STAGE(16, 32) FOLD_STAGE(8, 16)
    FOLD_STAGE(4, 8)   FOLD_STAGE(2, 4)   FOLD_STAGE(1, 2)
    #undef FOLD_STAGE
}

// ---------- memory machine (batch b): xi pre-computed, state LDS-resident ----------
__device__ void mem_body(SM& sm, int b, int tid,
        const float* __restrict__ gxi, float* __restrict__ glr)
{
    const int lane = tid & 63, wid = tid >> 6;

    // 0. stage xi row b (uncached vec4, one latency round)
    if (tid < 120) {
        v4f v4 = cload4(&gxi[(size_t)b * XIP + tid * 4]);
        *reinterpret_cast<v4f*>(&sm.sxi[tid * 4]) = v4;
    }
    __syncthreads();

    // 1. parse interface vector (bias already added by xi blocks)
    for (int i = tid; i < IF_; i += 256) {
        float vv = sm.sxi[i];
        if      (i < 256) sm.rkeys[i]     = tanhf(vv);
        else if (i < 260) sm.rstr[i-256]  = splus_(vv);
        else if (i < 324) sm.wkey[i-260]  = tanhf(vv);
        else if (i < 325) sm.sc[0]        = splus_(vv);
        else if (i < 389) sm.ev[i-325]    = sig_(vv);
        else if (i < 453) sm.wv[i-389]    = tanhf(vv);
        else if (i < 457) sm.fg[i-453]    = sig_(vv);
        else if (i < 458) sm.sc[1]        = sig_(vv);
        else if (i < 459) sm.sc[2]        = sig_(vv);
        else              sm.modes[i-459] = vv;
    }
    __syncthreads();

    // 2. usage update, sort key, pre-update norms, head norms, modes softmax
    unsigned long long key = ~0ull;
    if (tid < N_) {
        float p = 1.0f;
        #pragma unroll
        for (int r = 0; r < R_; ++r) p *= 1.0f - sm.fg[r] * sm.rw[r*N_ + tid];
        float uo = sm.usage[tid], w0 = sm.wwv[tid];
        float u = (uo + w0 - uo*w0) * p;
        sm.usage[tid] = u;
        unsigned int fb = __float_as_uint(u);
        fb = (fb & 0x80000000u) ? ~fb : (fb | 0x80000000u);
        key = ((unsigned long long)fb << 32) | (unsigned int)tid;
        float s = 0.0f;
        for (int w = 0; w < W_; ++w) { float m = sm.mem[tid*(W_+1)+w]; s += m*m; }
        sm.minv[tid] = 1.0f / (sqrtf(s) + EPSF);
    }
    if (tid >= 128 && tid < 128 + R_) {
        int r = tid - 128;
        float s = 0.0f;
        for (int w = 0; w < W_; ++w) { float kv = sm.rkeys[r*W_+w]; s += kv*kv; }
        sm.kinv[r] = 1.0f / (sqrtf(s) + EPSF);
    }
    if (tid == 132) {
        float s = 0.0f;
        for (int w = 0; w < W_; ++w) s += sm.wkey[w]*sm.wkey[w];
        sm.sc[5] = 1.0f / (sqrtf(s) + EPSF);
    }
    if (tid >= 136 && tid < 136 + R_) {
        int r = tid - 136;
        float m0 = sm.modes[r*3], m1 = sm.modes[r*3+1], m2 = sm.modes[r*3+2];
        float mx = fmaxf(m0, fmaxf(m1, m2));
        float e0 = expf(m0-mx), e1 = expf(m1-mx), e2 = expf(m2-mx);
        float inv = 1.0f / (e0 + e1 + e2);
        sm.modes[r*3] = e0*inv; sm.modes[r*3+1] = e1*inv; sm.modes[r*3+2] = e2*inv;
    }
    __syncthreads();

    // 3. write-content dot + register bitonic sort
    if (tid < N_) {
        float d = 0.0f;
        for (int w = 0; w < W_; ++w) d += sm.wkey[w] * sm.mem[tid*(W_+1)+w];
        sm.cw[tid] = d * sm.minv[tid] * sm.sc[5] * sm.sc[0];
    }
    for (int k = 2; k <= N_; k <<= 1) {
        for (int j = k >> 1; j > 0; j >>= 1) {
            unsigned long long pk;
            if (j == 64) {
                if (tid < N_) sm.key[tid] = key;
                __syncthreads();
                pk = (tid < N_) ? sm.key[tid ^ 64] : key;
                __syncthreads();
            } else {
                pk = shflx64(key, j);
            }
            bool lower = (tid & j) == 0;
            bool asc   = (tid & k) == 0;
            if ((key > pk) == (lower == asc)) key = pk;
        }
    }

    // 4. allocation via shfl product-scan; wave2 does write softmax
    float su = 0.0f, ex = 1.0f; int sidx = 0;
    if (tid < N_) {
        sidx = (int)(key & 0xffffffffu);
        su = sm.usage[sidx];
        float p = su;
        #pragma unroll
        for (int off = 1; off < 64; off <<= 1) {
            float pv = __shfl_up(p, off);
            if (lane >= off) p *= pv;
        }
        if (tid == 63) sm.sc[7] = p;
        float e = __shfl_up(p, 1);
        ex = (lane == 0) ? 1.0f : e;
    }
    __syncthreads();
    if (tid < N_) {
        if (tid >= 64) ex *= sm.sc[7];
        sm.alloc[sidx] = (1.0f - su) * ex;
    }
    if (wid == 2) {
        float v0 = sm.cw[lane], v1 = sm.cw[lane+64];
        float m = fmaxf(v0, v1);
        #pragma unroll
        for (int o = 32; o >= 1; o >>= 1) m = fmaxf(m, __shfl_xor(m, o));
        float e0 = expf(v0 - m), e1 = expf(v1 - m);
        float s = e0 + e1;
        #pragma unroll
        for (int o = 32; o >= 1; o >>= 1) s += __shfl_xor(s, o);
        sm.cw[lane] = e0; sm.cw[lane+64] = e1;
        if (lane == 0) sm.sc[4] = 1.0f / s;
    }
    __syncthreads();

    // 5. write weighting
    if (tid < N_) {
        float cwn = sm.cw[tid] * sm.sc[4];
        sm.wwv[tid] = sm.sc[2] * (sm.sc[1] * sm.alloc[tid] + (1.0f - sm.sc[1]) * cwn);
    }
    __syncthreads();

    // 6. memory update (in place) + sum_ww (wave3)
    for (int i = tid; i < N_*W_; i += 256) {
        int n = i >> 6, w = i & 63;
        float m = sm.mem[n*(W_+1)+w];
        sm.mem[n*(W_+1)+w] = m * (1.0f - sm.wwv[n]*sm.ev[w]) + sm.wwv[n]*sm.wv[w];
    }
    if (wid == 3) {
        float s = sm.wwv[lane] + sm.wwv[lane+64];
        #pragma unroll
        for (int o = 32; o >= 1; o >>= 1) s += __shfl_xor(s, o);
        if (lane == 0) sm.sc[6] = s;
    }
    __syncthreads();

    // 7. link update (LDS, in place)
    for (int i = tid; i < N_*N_; i += 256) {
        int row = i >> 7, col = i & 127;
        float wwr = sm.wwv[row];
        float nv = (1.0f - wwr - sm.wwv[col]) * sm.link[row][col] + wwr * sm.prc[col];
        if (row == col) nv = 0.0f;
        sm.link[row][col] = nv;
    }
    __syncthreads();

    // 7b. fwd/bwd dot passes
    for (int i = tid; i < R_*N_; i += 256) {
        int r = i >> 7, q = i & 127;
        float accf = 0.0f, accb = 0.0f;
        #pragma unroll 4
        for (int m2 = 0; m2 < 128; ++m2) {
            float rv = sm.rw[r*N_ + m2];
            accf = fmaf(sm.link[q][m2], rv, accf);
            accb = fmaf(sm.link[m2][q], rv, accb);
        }
        sm.fwd[i] = accf;
        sm.bwd[i] = accb;
    }
    __syncthreads();

    // 8. precedence + post-update norms
    if (tid < N_) {
        sm.prc[tid] = (1.0f - sm.sc[6]) * sm.prc[tid] + sm.wwv[tid];
        float s = 0.0f;
        for (int w = 0; w < W_; ++w) { float m = sm.mem[tid*(W_+1)+w]; s += m*m; }
        sm.minv[tid] = 1.0f / (sqrtf(s) + EPSF);
    }
    __syncthreads();

    // 9. read-content dots
    for (int i = tid; i < R_*N_; i += 256) {
        int r = i >> 7, n = i & 127;
        float d = 0.0f;
        for (int w = 0; w < W_; ++w) d += sm.rkeys[r*W_+w] * sm.mem[n*(W_+1)+w];
        sm.cr[i] = d * sm.minv[n] * sm.kinv[r] * sm.rstr[r];
    }
    __syncthreads();

    // 10. per-head softmax (wave = head)
    {
        int r = wid;
        float v0 = sm.cr[r*N_ + lane], v1 = sm.cr[r*N_ + lane + 64];
        float m = fmaxf(v0, v1);
        #pragma unroll
        for (int o = 32; o >= 1; o >>= 1) m = fmaxf(m, __shfl_xor(m, o));
        float e0 = expf(v0 - m), e1 = expf(v1 - m);
        float s = e0 + e1;
        #pragma unroll
        for (int o = 32; o >= 1; o >>= 1) s += __shfl_xor(s, o);
        sm.cr[r*N_ + lane] = e0; sm.cr[r*N_ + lane + 64] = e1;
        if (lane == 0) sm.m1[r] = sm.modes[r*3+1] / s;
    }
    __syncthreads();

    // 11. new read weights (persist)
    for (int i = tid; i < R_*N_; i += 256) {
        int r = i >> 7;
        sm.rw[i] = sm.modes[r*3] * sm.bwd[i] + sm.m1[r] * sm.cr[i] + sm.modes[r*3+2] * sm.fwd[i];
    }
    __syncthreads();

    // 12. read vectors -> lr[b][i] (uncached)
    for (int i = tid; i < R_*W_; i += 256) {
        int r = i >> 6, w = i & 63;
        float d = 0.0f;
        for (int n = 0; n < N_; ++n) d += sm.rw[r*N_ + n] * sm.mem[n*(W_+1)+w];
        cstore(&glr[(size_t)b * RW_ + i], d);
    }
}

// ---------- persistent kernel ----------
__global__ __launch_bounds__(256, 1) void k_fused(
        const float* __restrict__ x, const float* __restrict__ Wih,
        const float* __restrict__ Whh, const float* __restrict__ bih,
        const float* __restrict__ bhh, const float* __restrict__ Wif,
        const float* __restrict__ bif, const float* __restrict__ Wemb,
        const float* __restrict__ bemb, float* __restrict__ out,
        float* __restrict__ ws)
{
    __shared__ __align__(16) char smem_raw[(sizeof(SM) > sizeof(SA)) ? sizeof(SM) : sizeof(SA)];
    SA& sa = *reinterpret_cast<SA*>(smem_raw);
    SM& sm = *reinterpret_cast<SM*>(smem_raw);

    const int bid = blockIdx.x, tid = threadIdx.x;
    const int lane = tid & 63, wid = tid >> 6;

    float* h0  = ws + OFF_H0;
    float* h1  = ws + OFF_H1;
    float* lr  = ws + OFF_LR;
    float* gxi = ws + OFF_XI;
    unsigned* flagA = (unsigned*)(ws + OFF_FLAGA);
    unsigned* flagX = (unsigned*)(ws + OFF_FLAGX);
    unsigned* flagC = (unsigned*)(ws + OFF_FLAGC);

    if (bid < 128) {
        // ======================= GATES block: j = bid*4 + wid =======================
        const int j = bid * 4 + wid;
        if (tid < 128) sa.cc[tid >> 5][tid & 31] = 0.0f;
        float b0 = bih[j]        + bhh[j];
        float b1 = bih[H_ + j]   + bhh[H_ + j];
        float b2 = bih[2*H_ + j] + bhh[2*H_ + j];
        float b3 = bih[3*H_ + j] + bhh[3*H_ + j];
        __syncthreads();

        for (int t = 0; t < T_; ++t) {
            const float* hprev = (t & 1) ? h1 : h0;
            float*       hnew  = (t & 1) ? h0 : h1;
            float v[128];
            #pragma unroll
            for (int i = 0; i < 128; ++i) v[i] = 0.0f;

            // x tile (no dependency)
            stage_x(x, t, sa.act, tid);
            __syncthreads();
            tile_mac4(sa.act, Wih + (size_t)(0*H_+j)*512, Wih + (size_t)(1*H_+j)*512,
                              Wih + (size_t)(2*H_+j)*512, Wih + (size_t)(3*H_+j)*512, lane, v);
            // h(t-1) tiles — need gates flags >= t (overlaps mem(t-1))
            if (tid < 128) { while (uload(&flagA[tid*32]) < (unsigned)t) __builtin_amdgcn_s_sleep(8); }
            __syncthreads();
            stage_coh(hprev, H_, 0, sa.act, tid);
            __syncthreads();
            tile_mac4(sa.act, Whh + (size_t)(0*H_+j)*512, Whh + (size_t)(1*H_+j)*512,
                              Whh + (size_t)(2*H_+j)*512, Whh + (size_t)(3*H_+j)*512, lane, v);
            __syncthreads();
            stage_coh(hprev, H_, 256, sa.act, tid);
            __syncthreads();
            tile_mac4(sa.act, Whh + (size_t)(0*H_+j)*512 + 256, Whh + (size_t)(1*H_+j)*512 + 256,
                              Whh + (size_t)(2*H_+j)*512 + 256, Whh + (size_t)(3*H_+j)*512 + 256, lane, v);
            // lr(t-1) tile — needs mem(t-1)
            if (tid < 32) { while (uload(&flagC[tid*32]) < (unsigned)t) __builtin_amdgcn_s_sleep(8); }
            __syncthreads();
            stage_coh(lr, RW_, 0, sa.act, tid);
            __syncthreads();
            tile_mac4(sa.act, Wih + (size_t)(0*H_+j)*512 + 256, Wih + (size_t)(1*H_+j)*512 + 256,
                              Wih + (size_t)(2*H_+j)*512 + 256, Wih + (size_t)(3*H_+j)*512 + 256, lane, v);
            fold128(v, lane);
            int r = (lane >> 4) & 3, bb0 = (lane & 15) * 2;
            sa.sg[wid][r][bb0]     = v[0];
            sa.sg[wid][r][bb0 + 1] = v[1];
            __syncthreads();
            if (lane < 32) {
                int b = lane;
                float ai = sa.sg[wid][0][b] + b0;
                float af = sa.sg[wid][1][b] + b1;
                float ag = sa.sg[wid][2][b] + b2;
                float ao = sa.sg[wid][3][b] + b3;
                float ig = sig_(ai), fg = sig_(af), gg = tanhf(ag), og = sig_(ao);
                float cn = fg * sa.cc[wid][b] + ig * gg;
                sa.cc[wid][b] = cn;
                sa.hst[wid][b] = og * tanhf(cn);
            }
            __syncthreads();
            if (tid < 32) {
                int b = tid;
                v4f hv;
                hv.x = sa.hst[0][b]; hv.y = sa.hst[1][b];
                hv.z = sa.hst[2][b]; hv.w = sa.hst[3][b];
                cstore4(&hnew[(size_t)b * H_ + bid * 4], hv);
            }
            post_flag(&flagA[bid * 32], (unsigned)(t + 1));
        }
    } else if (bid < 144) {
        // ======================= OUT block: rows (bid-128)*16 + wid*4 ===============
        const int rb = (bid - 128) * 16 + wid * 4;
        const float* w0 = Wemb + (size_t)(rb + 0) * 768;
        const float* w1 = Wemb + (size_t)(rb + 1) * 768;
        const float* w2 = Wemb + (size_t)(rb + 2) * 768;
        const float* w3 = Wemb + (size_t)(rb + 3) * 768;

        for (int t = 0; t < T_; ++t) {
            const float* hprev = (t & 1) ? h1 : h0;
            if (t > 0) {
                float v[128];
                #pragma unroll
                for (int i = 0; i < 128; ++i) v[i] = 0.0f;
                if (tid < 128) { while (uload(&flagA[tid*32]) < (unsigned)t) __builtin_amdgcn_s_sleep(8); }
                __syncthreads();
                stage_coh(hprev, H_, 0, sa.act, tid);
                __syncthreads();
                tile_mac4(sa.act, w0, w1, w2, w3, lane, v);
                __syncthreads();
                stage_coh(hprev, H_, 256, sa.act, tid);
                __syncthreads();
                tile_mac4(sa.act, w0 + 256, w1 + 256, w2 + 256, w3 + 256, lane, v);
                if (tid < 32) { while (uload(&flagC[tid*32]) < (unsigned)t) __builtin_amdgcn_s_sleep(8); }
                __syncthreads();
                stage_coh(lr, RW_, 0, sa.act, tid);
                __syncthreads();
                tile_mac4(sa.act, w0 + 512, w1 + 512, w2 + 512, w3 + 512, lane, v);
                fold128(v, lane);
                int rloc = (lane >> 4) & 3, bb0 = (lane & 15) * 2;
                int row = rb + rloc;
                float bb = bemb[row];
                out[((size_t)bb0       * T_ + (t-1)) * FOUT_ + row] = v[0] + bb;
                out[((size_t)(bb0 + 1) * T_ + (t-1)) * FOUT_ + row] = v[1] + bb;
            }
            post_flag(&flagA[bid * 32], (unsigned)(t + 1));
        }
        // tail: out(T-1)
        {
            if (tid < 32) { while (uload(&flagC[tid*32]) < (unsigned)T_) __builtin_amdgcn_s_sleep(8); }
            __syncthreads();
            float v[128];
            #pragma unroll
            for (int i = 0; i < 128; ++i) v[i] = 0.0f;
            stage_coh(h0, H_, 0, sa.act, tid);
            __syncthreads();
            tile_mac4(sa.act, w0, w1, w2, w3, lane, v);
            __syncthreads();
            stage_coh(h0, H_, 256, sa.act, tid);
            __syncthreads();
            tile_mac4(sa.act, w0 + 256, w1 + 256, w2 + 256, w3 + 256, lane, v);
            __syncthreads();
            stage_coh(lr, RW_, 0, sa.act, tid);
            __syncthreads();
            tile_mac4(sa.act, w0 + 512, w1 + 512, w2 + 512, w3 + 512, lane, v);
            fold128(v, lane);
            int rloc = (lane >> 4) & 3, bb0 = (lane & 15) * 2;
            int row = rb + rloc;
            float bb = bemb[row];
            out[((size_t)bb0       * T_ + (T_-1)) * FOUT_ + row] = v[0] + bb;
            out[((size_t)(bb0 + 1) * T_ + (T_-1)) * FOUT_ + row] = v[1] + bb;
        }
    } else if (bid < 176) {
        // ======================= XI block: rows (bid-144)*16 + wid*4 ================
        const int rb = (bid - 144) * 16 + wid * 4;
        int r0 = min(rb + 0, IF_ - 1), r1 = min(rb + 1, IF_ - 1);
        int r2 = min(rb + 2, IF_ - 1), r3 = min(rb + 3, IF_ - 1);
        const float* w0 = Wif + (size_t)r0 * 512;
        const float* w1 = Wif + (size_t)r1 * 512;
        const float* w2 = Wif + (size_t)r2 * 512;
        const float* w3 = Wif + (size_t)r3 * 512;

        for (int t = 0; t < T_; ++t) {
            float* hnew = (t & 1) ? h0 : h1;
            float v[128];
            #pragma unroll
            for (int i = 0; i < 128; ++i) v[i] = 0.0f;
            // wait gates to publish h(t); mem(t-1) done reading xi is transitively implied
            if (tid < 128) { while (uload(&flagA[tid*32]) < (unsigned)(t+1)) __builtin_amdgcn_s_sleep(8); }
            __syncthreads();
            stage_coh(hnew, H_, 0, sa.act, tid);
            __syncthreads();
            tile_mac4(sa.act, w0, w1, w2, w3, lane, v);
            __syncthreads();
            stage_coh(hnew, H_, 256, sa.act, tid);
            __syncthreads();
            tile_mac4(sa.act, w0 + 256, w1 + 256, w2 + 256, w3 + 256, lane, v);
            fold128(v, lane);
            int rloc = (lane >> 4) & 3, bb0 = (lane & 15) * 2;
            int row = rb + rloc;
            if (row < IF_) {
                float bb = bif[row];
                cstore(&gxi[(size_t)bb0       * XIP + row], v[0] + bb);
                cstore(&gxi[(size_t)(bb0 + 1) * XIP + row], v[1] + bb);
            }
            post_flag(&flagX[(bid - 144) * 32], (unsigned)(t + 1));
        }
    } else {
        // ======================= MEM block: batch b = bid-176 =======================
        const int b = bid - 176;
        float* z = (float*)&sm;
        for (int i = tid; i < (int)(sizeof(SM)/4); i += 256) z[i] = 0.0f;
        __syncthreads();

        for (int t = 0; t < T_; ++t) {
            unsigned val = (unsigned)(t + 1);
            // wait: 32 xi flags (xi(t) written, implies gates done) + 16 out flags (lr WAR)
            if (tid < 32) {
                while (uload(&flagX[tid * 32]) < val) __builtin_amdgcn_s_sleep(8);
            } else if (tid >= 64 && tid < 80) {
                while (uload(&flagA[(128 + (tid - 64)) * 32]) < val) __builtin_amdgcn_s_sleep(8);
            }
            __syncthreads();
            mem_body(sm, b, tid, gxi, lr);
            post_flag(&flagC[b * 32], val);
        }
    }
}

extern "C" void kernel_launch(void* const* d_in, const int* in_sizes, int n_in,
                              void* d_out, int out_size, void* d_ws, size_t ws_size,
                              hipStream_t stream)
{
    const float* x    = (const float*)d_in[0];
    const float* Wih  = (const float*)d_in[1];
    const float* Whh  = (const float*)d_in[2];
    const float* bih  = (const float*)d_in[3];
    const float* bhh  = (const float*)d_in[4];
    const float* Wif  = (const float*)d_in[5];
    const float* bif  = (const float*)d_in[6];
    const float* Wemb = (const float*)d_in[7];
    const float* bemb = (const float*)d_in[8];
    float* out = (float*)d_out;
    float* ws  = (float*)d_ws;

    k_init<<<64, 256, 0, stream>>>(ws, WS_TOTAL);

    k_fused<<<dim3(NBLK), dim3(256), 0, stream>>>(x, Wih, Whh, bih, bhh,
                                                  Wif, bif, Wemb, bemb, out, ws);
}